// Round 8
// baseline (472.641 us; speedup 1.0000x reference)
//
#include <hip/hip_runtime.h>

// GCN: out = A*(relu(A*(X*W1)+b1)*W2)+b2, A sparse COO, sorted row[].
// N=100000, E=3200000, IN=256, HID=256, OUT=64.
// Pipeline (7 launches, int8 gather sources):
//   setup: rowptr + W1T + W2T
//   gemm1: Q1,s1 = int8rowquant(bf16(X)@W1)  (512thr, BM=128 BN=256,
//          LDS-repacked coalesced int8 stores)
//   prep1: ew = {col<<8, vals*s1[col]}
//   spmm1: H = relu(A@deq(Q1)+b1) -> bf16
//   gemm2: Q2,s2 = int8rowquant(H@W2)        (256thr, BM=128 BN=64, LDS repack)
//   prep2: ew = {col<<6, vals*s2[col]}
//   spmm2: out = A@deq(Q2)+b2 -> fp32

constexpr int IN_SIZE = 256;
constexpr int HID = 256;
constexpr int OUTF = 64;

typedef __bf16 bf16x8 __attribute__((ext_vector_type(8)));
typedef float f32x4 __attribute__((ext_vector_type(4)));

__device__ __forceinline__ ushort f2b(float f) {
    uint u = __float_as_uint(f);
    uint r = (u + 0x7fffu + ((u >> 16) & 1u)) >> 16;   // RNE
    return (ushort)r;
}
__device__ __forceinline__ float b2f(ushort h) {
    return __uint_as_float(((uint)h) << 16);
}

// ---------------------------------------------------------------------------
// setup: blocks [0,rpB): row_ptr; [rpB,rpB+256): W1T; [rpB+256,rpB+320): W2T
__global__ void setup_kernel(const int* __restrict__ row, int* __restrict__ rp,
                             const float* __restrict__ W1, ushort* __restrict__ W1T,
                             const float* __restrict__ W2, ushort* __restrict__ W2T,
                             int n, int E, int rpB) {
    int b = blockIdx.x;
    if (b < rpB) {
        int i = b * 256 + threadIdx.x;
        if (i > n) return;
        int lo = 0, hi = E;
        while (lo < hi) {
            int mid = (lo + hi) >> 1;
            if (row[mid] < i) lo = mid + 1; else hi = mid;
        }
        rp[i] = lo;
    } else if (b < rpB + 256) {
        int nn = b - rpB;
        int k = threadIdx.x;
        W1T[(size_t)nn * 256 + k] = f2b(W1[(size_t)k * 256 + nn]);
    } else {
        int nn = b - rpB - 256;
        int k = threadIdx.x;
        W2T[(size_t)nn * 256 + k] = f2b(W2[(size_t)k * 64 + nn]);
    }
}

// prep: ew[e] = {col[e]<<shift (byte offset into Q), vals[e]*s[col[e]]}
__global__ void prep_edges(const float* __restrict__ vals, const int* __restrict__ col,
                           const float* __restrict__ s, int2* __restrict__ ew,
                           int E, int shift) {
    int e = blockIdx.x * 256 + threadIdx.x;
    if (e >= E) return;
    int c = col[e];
    ew[e] = make_int2(c << shift, __float_as_int(vals[e] * s[c]));
}

// ---------------------------------------------------------------------------
// GEMM1+quant: Q[M,256] int8, s1[M] from bf16(X_f32[M,256]) @ Bt[256,256]^T.
// BM=128, BN=256, BK=32. 512 threads = 8 waves 2x4; wave tile 64x64.
// Epilogue: row absmax -> s1; int8 quant repacked through LDS (union with
// As/Bs staging) -> coalesced uint4 stores.
__global__ __launch_bounds__(512)
void gemm1_q(const float* __restrict__ A, const ushort* __restrict__ Bt,
             char* __restrict__ Q, float* __restrict__ s1, int M) {
    constexpr int K = 256;
    __shared__ ushort smem[16384];      // As[128*40] | Bs[256*40]  (30.7 KB)
    __shared__ float red[4][128];       //  ... reused as Qs[128*256] (32 KB)
    __shared__ float fin[128];
    ushort* As = smem;
    ushort* Bs = smem + 128 * 40;
    char*   Qs = (char*)smem;
    const int tid = threadIdx.x;
    const int wave = tid >> 6, lane = tid & 63;
    const int quad = lane >> 4, l = lane & 15;
    const int wr = wave >> 2, wc = wave & 3;     // 2 x 4 wave grid
    const int m0 = blockIdx.x * 128;

    const int ar = tid >> 2;
    const int ak = (tid & 3) * 8;
    const size_t aoff = (size_t)min(m0 + ar, M - 1) * K + ak;
    const int bn = tid >> 2;
    const int bkp = (tid & 3) * 8;

    f32x4 acc[4][4] = {};

    for (int k0 = 0; k0 < K; k0 += 32) {
        float4 a0 = *(const float4*)(A + aoff + k0);
        float4 a1 = *(const float4*)(A + aoff + k0 + 4);
        uint4 bv0 = *(const uint4*)(Bt + (size_t)bn * K + k0 + bkp);
        uint4 bv1 = *(const uint4*)(Bt + (size_t)(bn + 128) * K + k0 + bkp);
        uint4 pa;
        pa.x = (uint)f2b(a0.x) | ((uint)f2b(a0.y) << 16);
        pa.y = (uint)f2b(a0.z) | ((uint)f2b(a0.w) << 16);
        pa.z = (uint)f2b(a1.x) | ((uint)f2b(a1.y) << 16);
        pa.w = (uint)f2b(a1.z) | ((uint)f2b(a1.w) << 16);
        __syncthreads();
        *(uint4*)&As[ar * 40 + ak] = pa;
        *(uint4*)&Bs[bn * 40 + bkp] = bv0;
        *(uint4*)&Bs[(bn + 128) * 40 + bkp] = bv1;
        __syncthreads();

        bf16x8 af[4], bfr[4];
#pragma unroll
        for (int mt = 0; mt < 4; ++mt)
            af[mt] = *(const bf16x8*)&As[(wr * 64 + mt * 16 + l) * 40 + quad * 8];
#pragma unroll
        for (int nt = 0; nt < 4; ++nt)
            bfr[nt] = *(const bf16x8*)&Bs[(wc * 64 + nt * 16 + l) * 40 + quad * 8];
#pragma unroll
        for (int mt = 0; mt < 4; ++mt)
#pragma unroll
            for (int nt = 0; nt < 4; ++nt)
                acc[mt][nt] = __builtin_amdgcn_mfma_f32_16x16x32_bf16(
                    af[mt], bfr[nt], acc[mt][nt], 0, 0, 0);
    }

    // per-lane row absmax over this wave's 64 cols
    float rmax[4][4];
#pragma unroll
    for (int mt = 0; mt < 4; ++mt)
#pragma unroll
        for (int reg = 0; reg < 4; ++reg) {
            float m = 0.f;
#pragma unroll
            for (int nt = 0; nt < 4; ++nt)
                m = fmaxf(m, fabsf(acc[mt][nt][reg]));
            rmax[mt][reg] = m;
        }
#pragma unroll
    for (int s = 1; s <= 8; s <<= 1)
#pragma unroll
        for (int mt = 0; mt < 4; ++mt)
#pragma unroll
            for (int reg = 0; reg < 4; ++reg)
                rmax[mt][reg] = fmaxf(rmax[mt][reg], __shfl_xor(rmax[mt][reg], s));
    if (l < 4) {
#pragma unroll
        for (int mt = 0; mt < 4; ++mt)
            red[wc][wr * 64 + mt * 16 + quad * 4 + l] = rmax[mt][l];
    }
    __syncthreads();
    if (tid < 128) {
        float m = fmaxf(fmaxf(red[0][tid], red[1][tid]),
                        fmaxf(red[2][tid], red[3][tid]));
        fin[tid] = m;
        int r = m0 + tid;
        if (r < M) s1[r] = m * (1.f / 127.f);
    }
    __syncthreads();   // fin ready; As/Bs dead -> reuse as Qs

    // quantize acc -> LDS byte tile
#pragma unroll
    for (int mt = 0; mt < 4; ++mt)
#pragma unroll
        for (int reg = 0; reg < 4; ++reg) {
            int rl = wr * 64 + mt * 16 + quad * 4 + reg;
            float m = fin[rl];
            float inv = m > 0.f ? 127.f / m : 0.f;
#pragma unroll
            for (int nt = 0; nt < 4; ++nt) {
                int c = wc * 64 + nt * 16 + l;
                Qs[rl * 256 + c] = (char)(int)rintf(acc[mt][nt][reg] * inv);
            }
        }
    __syncthreads();

    // coalesced stores: 32 KB tile, 512 thr x 16B x 4 iters
#pragma unroll
    for (int it = 0; it < 4; ++it) {
        int off = it * 8192 + tid * 16;
        int rl = off >> 8;
        if (m0 + rl < M)
            *(uint4*)(Q + (size_t)(m0 + rl) * 256 + (off & 255)) =
                *(const uint4*)(Qs + off);
    }
}

// ---------------------------------------------------------------------------
// GEMM2+quant: Q[M,64] int8, s2[M] from A[M,256] bf16 @ Bt[64,256]^T.
// BM=128, BN=64, BK=32; 256 threads = 4 waves 2x2. Same LDS-repack epilogue.
__global__ __launch_bounds__(256, 4)
void gemm2_q(const ushort* __restrict__ A, const ushort* __restrict__ Bt,
             char* __restrict__ Q, float* __restrict__ s2, int M) {
    constexpr int K = 256;
    __shared__ ushort smem[7680];       // As[128*40] | Bs[64*40] (15.4 KB)
    __shared__ float red[2][128];       //  ... reused as Qs[128*64] (8 KB)
    __shared__ float fin[128];
    ushort* As = smem;
    ushort* Bs = smem + 128 * 40;
    char*   Qs = (char*)smem;
    const int tid = threadIdx.x;
    const int wave = tid >> 6, lane = tid & 63;
    const int quad = lane >> 4, l = lane & 15;
    const int wr = wave >> 1, wc = wave & 1;
    const int m0 = blockIdx.x * 128;

    const int crow = tid >> 2;
    const int cpart = (tid & 3) * 8;
    const size_t aoff0 = (size_t)min(m0 + crow, M - 1) * K + cpart;
    const size_t aoff1 = (size_t)min(m0 + crow + 64, M - 1) * K + cpart;
    const size_t boff  = (size_t)crow * K + cpart;

    f32x4 acc[4][2] = {};

    for (int k0 = 0; k0 < K; k0 += 32) {
        uint4 a0 = *(const uint4*)(A + aoff0 + k0);
        uint4 a1 = *(const uint4*)(A + aoff1 + k0);
        uint4 b0 = *(const uint4*)(Bt + boff + k0);
        __syncthreads();
        *(uint4*)&As[crow * 40 + cpart] = a0;
        *(uint4*)&As[(crow + 64) * 40 + cpart] = a1;
        *(uint4*)&Bs[crow * 40 + cpart] = b0;
        __syncthreads();

        bf16x8 af[4], bfr[2];
        const ushort* ab = &As[(wr * 64 + l) * 40 + quad * 8];
#pragma unroll
        for (int mt = 0; mt < 4; ++mt)
            af[mt] = *(const bf16x8*)(ab + mt * 16 * 40);
        const ushort* bb = &Bs[(wc * 32 + l) * 40 + quad * 8];
#pragma unroll
        for (int nt = 0; nt < 2; ++nt)
            bfr[nt] = *(const bf16x8*)(bb + nt * 16 * 40);
#pragma unroll
        for (int mt = 0; mt < 4; ++mt)
#pragma unroll
            for (int nt = 0; nt < 2; ++nt)
                acc[mt][nt] = __builtin_amdgcn_mfma_f32_16x16x32_bf16(
                    af[mt], bfr[nt], acc[mt][nt], 0, 0, 0);
    }

    float rmax[4][4];
#pragma unroll
    for (int mt = 0; mt < 4; ++mt)
#pragma unroll
        for (int reg = 0; reg < 4; ++reg)
            rmax[mt][reg] = fmaxf(fabsf(acc[mt][0][reg]), fabsf(acc[mt][1][reg]));
#pragma unroll
    for (int s = 1; s <= 8; s <<= 1)
#pragma unroll
        for (int mt = 0; mt < 4; ++mt)
#pragma unroll
            for (int reg = 0; reg < 4; ++reg)
                rmax[mt][reg] = fmaxf(rmax[mt][reg], __shfl_xor(rmax[mt][reg], s));
    if (l < 4) {
#pragma unroll
        for (int mt = 0; mt < 4; ++mt)
            red[wc][wr * 64 + mt * 16 + quad * 4 + l] = rmax[mt][l];
    }
    __syncthreads();
    if (tid < 128) {
        float m = fmaxf(red[0][tid], red[1][tid]);
        fin[tid] = m;
        int r = m0 + tid;
        if (r < M) s2[r] = m * (1.f / 127.f);
    }
    __syncthreads();   // As/Bs dead -> Qs

#pragma unroll
    for (int mt = 0; mt < 4; ++mt)
#pragma unroll
        for (int reg = 0; reg < 4; ++reg) {
            int rl = wr * 64 + mt * 16 + quad * 4 + reg;
            float m = fin[rl];
            float inv = m > 0.f ? 127.f / m : 0.f;
#pragma unroll
            for (int nt = 0; nt < 2; ++nt) {
                int c = wc * 32 + nt * 16 + l;
                Qs[rl * 64 + c] = (char)(int)rintf(acc[mt][nt][reg] * inv);
            }
        }
    __syncthreads();

    // coalesced stores: 8 KB tile, 256 thr x 16B x 2 iters
#pragma unroll
    for (int it = 0; it < 2; ++it) {
        int off = it * 4096 + tid * 16;
        int rl = off >> 6;
        if (m0 + rl < M)
            *(uint4*)(Q + (size_t)(m0 + rl) * 64 + (off & 63)) =
                *(const uint4*)(Qs + off);
    }
}

// ---------------------------------------------------------------------------
// SpMM layer1: H = relu(sum_e w_e * Q1[c_e] + b1). Wave per node; lane = 4
// features (4B gather/edge); one 8B ew load per edge; 8-edge unroll.
// ew.x is a pre-shifted byte offset (col*256).
__global__ __launch_bounds__(256)
void spmm1_q(const char* __restrict__ Q, const int2* __restrict__ ew,
             const int* __restrict__ rp, const float* __restrict__ bias,
             ushort* __restrict__ H, int n) {
    const int wave = threadIdx.x >> 6;
    const int lane = threadIdx.x & 63;
    const int node = blockIdx.x * 4 + wave;
    if (node >= n) return;
    const int e0 = rp[node], e1 = rp[node + 1];
    float a0 = 0.f, a1 = 0.f, a2 = 0.f, a3 = 0.f;
    int e = e0;
    for (; e + 7 < e1; e += 8) {
#pragma unroll
        for (int u = 0; u < 8; ++u) {
            int2 m = ew[e + u];
            float w = __int_as_float(m.y);
            char4 q = *(const char4*)(Q + (size_t)(uint)m.x + lane * 4);
            a0 += w * (float)q.x;
            a1 += w * (float)q.y;
            a2 += w * (float)q.z;
            a3 += w * (float)q.w;
        }
    }
    for (; e < e1; ++e) {
        int2 m = ew[e];
        float w = __int_as_float(m.y);
        char4 q = *(const char4*)(Q + (size_t)(uint)m.x + lane * 4);
        a0 += w * (float)q.x;
        a1 += w * (float)q.y;
        a2 += w * (float)q.z;
        a3 += w * (float)q.w;
    }
    float4 b = *(const float4*)(bias + lane * 4);
    ushort4 r;
    r.x = f2b(fmaxf(a0 + b.x, 0.f));
    r.y = f2b(fmaxf(a1 + b.y, 0.f));
    r.z = f2b(fmaxf(a2 + b.z, 0.f));
    r.w = f2b(fmaxf(a3 + b.w, 0.f));
    *(ushort4*)(H + (size_t)node * 256 + lane * 4) = r;
}

// ---------------------------------------------------------------------------
// SpMM layer2: out = sum_e w_e * Q2[c_e] + b2. Wave per node; lane = feature
// (1B gather/edge); ew.x pre-shifted (col*64); 16-edge unroll.
__global__ __launch_bounds__(256)
void spmm2_q(const char* __restrict__ Q, const int2* __restrict__ ew,
             const int* __restrict__ rp, const float* __restrict__ bias,
             float* __restrict__ O, int n) {
    const int wave = threadIdx.x >> 6;
    const int lane = threadIdx.x & 63;
    const int node = blockIdx.x * 4 + wave;
    if (node >= n) return;
    const int e0 = rp[node], e1 = rp[node + 1];
    float acc = 0.f;
    int e = e0;
    for (; e + 15 < e1; e += 16) {
#pragma unroll
        for (int u = 0; u < 16; ++u) {
            int2 m = ew[e + u];
            acc += __int_as_float(m.y) * (float)Q[(size_t)(uint)m.x + lane];
        }
    }
    for (; e + 3 < e1; e += 4) {
#pragma unroll
        for (int u = 0; u < 4; ++u) {
            int2 m = ew[e + u];
            acc += __int_as_float(m.y) * (float)Q[(size_t)(uint)m.x + lane];
        }
    }
    for (; e < e1; ++e) {
        int2 m = ew[e];
        acc += __int_as_float(m.y) * (float)Q[(size_t)(uint)m.x + lane];
    }
    O[(size_t)node * 64 + lane] = acc + bias[lane];
}

// ---------------------------------------------------------------------------
static inline size_t alignup(size_t x) { return (x + 255) & ~(size_t)255; }

extern "C" void kernel_launch(void* const* d_in, const int* in_sizes, int n_in,
                              void* d_out, int out_size, void* d_ws, size_t ws_size,
                              hipStream_t stream) {
    const float* X  = (const float*)d_in[0];
    const float* ev = (const float*)d_in[1];
    const float* W1 = (const float*)d_in[2];
    const float* b1 = (const float*)d_in[3];
    const float* W2 = (const float*)d_in[4];
    const float* b2 = (const float*)d_in[5];
    const int*  row = (const int*)d_in[6];
    const int*  col = (const int*)d_in[7];
    float* out = (float*)d_out;

    const int n = in_sizes[0] / IN_SIZE;   // 100000
    const int E = in_sizes[1];             // 3200000

    char* p = (char*)d_ws;
    ushort* H    = (ushort*)p; p += alignup((size_t)n * HID * 2);
    char*   Q1   = (char*)p;   p += alignup((size_t)n * HID);
    float*  s1   = (float*)p;  p += alignup((size_t)n * 4);
    char*   Q2   = (char*)p;   p += alignup((size_t)n * OUTF);
    float*  s2   = (float*)p;  p += alignup((size_t)n * 4);
    ushort* W1T  = (ushort*)p; p += alignup((size_t)IN_SIZE * HID * 2);
    ushort* W2T  = (ushort*)p; p += alignup((size_t)HID * OUTF * 2);
    int*    rp   = (int*)p;    p += alignup((size_t)(n + 1) * 4);
    int2*   ewb  = (int2*)p;   p += alignup((size_t)E * 8);

    const int rpB = (n + 1 + 255) / 256;
    setup_kernel<<<rpB + 256 + 64, 256, 0, stream>>>(row, rp, W1, W1T, W2, W2T,
                                                     n, E, rpB);

    // Q1,s1 = int8rowquant(bf16(X) @ W1)
    gemm1_q<<<(n + 127) / 128, 512, 0, stream>>>(X, W1T, Q1, s1, n);

    // ew = {col<<8, vals*s1[col]}
    prep_edges<<<(E + 255) / 256, 256, 0, stream>>>(ev, col, s1, ewb, E, 8);

    // H = relu(A @ deq(Q1) + b1)
    spmm1_q<<<(n + 3) / 4, 256, 0, stream>>>(Q1, ewb, rp, b1, H, n);

    // Q2,s2 = int8rowquant(H @ W2)
    gemm2_q<<<(n + 127) / 128, 256, 0, stream>>>(H, W2T, Q2, s2, n);

    // ew = {col<<6, vals*s2[col]}
    prep_edges<<<(E + 255) / 256, 256, 0, stream>>>(ev, col, s2, ewb, E, 6);

    // out = A @ deq(Q2) + b2
    spmm2_q<<<(n + 3) / 4, 256, 0, stream>>>(Q2, ewb, rp, b2, out, n);
}